// Round 2
// baseline (294.686 us; speedup 1.0000x reference)
//
#include <hip/hip_runtime.h>
#include <stdint.h>

// z: [16,1024,256] fp32 -> N=16384 rows, D=256
// embedding: [8192,256] fp32 -> K=8192 codes
// out = [ z_q (4194304 f32) | loss (1 f32) | indices (16384 as f32) ]
#define N_ROWS   16384
#define DIM      256
#define N_CODES  8192
#define ZQ_ELEMS 4194304

typedef _Float16 f16x8 __attribute__((ext_vector_type(8)));
typedef _Float16 f16x4 __attribute__((ext_vector_type(4)));
typedef float    f32x16 __attribute__((ext_vector_type(16)));
typedef unsigned long long u64;

// ---- workspace (bytes): et 8.52 MB | pkeys 256 KB ----
// et layout in f16x8 units (16 B):
//   hi plane: ksg*16384 + code*2 + h     (ksg 0..15, h 0..1 -> k-octet 2ksg+h)
//   lo plane: +262144
//   aug:      524288 + code  ({||e||^2_hi, ||e||^2_lo, 0...})
// (zeros slab removed: aug-MFMA B rows 8..15 are 0, so hi1=1 lanes' A values
//  are multiplied by 0 -> any finite data is fine; norms are finite f16.)
#define WS_ET  0
#define WS_PK  (8650752)

static __device__ __forceinline__ u64 packkey(float d, int c) {
    unsigned int u = __float_as_uint(d);
    u ^= ((unsigned int)((int)u >> 31)) | 0x80000000u;   // monotone float map
    return ((u64)u << 32) | (unsigned int)c;             // min => (dist, then idx)
}

// ---------------- prep: e-only, 256 fat blocks x 32 codes ----------------
// LDS transpose with row stride 272 halves (544 B = 34 quads, odd*2 -> the
// readout's (cl,h) lane pattern maps to quad (2cl+h)&7: conflict-free).
// et stores are 1-KB contiguous per wave.
__global__ void vq_prep(const float* __restrict__ emb, _Float16* __restrict__ et,
                        float* __restrict__ loss_ptr) {
    __shared__ _Float16 sh[2][32][272];          // 34,816 B
    const int t = threadIdx.x, w = t >> 6, l = t & 63;
    if (blockIdx.x == 0 && t == 0) *loss_ptr = 0.0f;
    const int code0 = blockIdx.x * 32;
    #pragma unroll
    for (int j = 0; j < 8; ++j) {
        const int cl = w * 8 + j;
        float4 v = *(const float4*)(emb + (size_t)(code0 + cl) * DIM + l * 4);
        float xs[4] = {v.x, v.y, v.z, v.w};
        f16x4 hh, lo;
        float s = 0.0f;
        #pragma unroll
        for (int i = 0; i < 4; ++i) {
            _Float16 h = (_Float16)xs[i];
            hh[i] = h;
            lo[i] = (_Float16)(xs[i] - (float)h);
            s += xs[i] * xs[i];
        }
        *(f16x4*)&sh[0][cl][l * 4] = hh;
        *(f16x4*)&sh[1][cl][l * 4] = lo;
        #pragma unroll
        for (int off = 32; off > 0; off >>= 1) s += __shfl_down(s, off, 64);
        if (l == 0) {                            // aug: {norm_hi, norm_lo, 0..}
            _Float16 nh = (_Float16)s;
            _Float16 nl = (_Float16)(s - (float)nh);
            f16x8 aug;
            #pragma unroll
            for (int i = 0; i < 8; ++i) aug[i] = (_Float16)0;
            aug[0] = nh; aug[1] = nl;
            *(f16x8*)(et + ((size_t)524288 + code0 + cl) * 8) = aug;
        }
    }
    __syncthreads();
    #pragma unroll
    for (int pp = 0; pp < 8; ++pp) {             // 2048 units, 1-KB coalesced stores
        const int gi = pp * 256 + t;
        const int p = gi >> 10, ks = (gi >> 6) & 15, cl = (gi >> 1) & 31, h = gi & 1;
        f16x8 frag = *(const f16x8*)&sh[p][cl][ks * 16 + h * 8];
        const size_t unit = (size_t)p * 262144 + (size_t)ks * 16384
                          + (size_t)(code0 + cl) * 2 + h;
        *(f16x8*)(et + unit * 8) = frag;
    }
}

// ---------------- main: 64-row blocks, 2 blocks/CU (4 waves/SIMD) ----------------
// grid 512 = 256 row-blocks x 2 code-splits; 512 threads (8 waves).
// z staged in-kernel from f32 global (-2z hi/lo), LDS row-major stride 1040 B:
//   byte(row, koct, p, half8) = row*1040 + p*512 + koct*16 + half8*8
// 1040 = 16*65 (65 odd) -> b128 read quad = lane&7 -> conflict-free; the
// staging ds_write_b64 is lane-linear. B read = one vaddr (lo5*1040 + hi1*16)
// + imm (nt*33280 + ksg*32 [+512 lo]), max 34272 < 64 KB.
// A = e from global (L2-served, contiguous 1-KB wave segments).
// Aug-MFMA-first with C=0 initializes acc AND adds ||e||^2.
// run fold in LDS at +66560; total dynamic LDS 70,656 B -> 2 blocks/CU.
__global__ __launch_bounds__(512, 4)
void vq_main(const float* __restrict__ z, const _Float16* __restrict__ et,
             u64* __restrict__ pkeys) {
    extern __shared__ char smem[];
    u64* run = (u64*)(smem + 66560);             // [8][64]

    const int tid = threadIdx.x;
    const int w = tid >> 6, L = tid & 63, lo5 = L & 31, hi1 = L >> 5;
    const int rb = blockIdx.x >> 1, sp = blockIdx.x & 1;
    const int row0 = rb * 64, codeS = sp * 4096;

    // ---- stage z: coalesced f32 loads -> (-2z) hi/lo -> lane-linear ds_write ----
    const float* zr = z + (size_t)row0 * DIM;
    #pragma unroll
    for (int jj = 0; jj < 8; ++jj) {
        const int idx = jj * 512 + tid;          // float4 index in [0,4096)
        const int r = idx >> 6, q = idx & 63;    // row, dim-quad
        float4 v = *(const float4*)(zr + (size_t)r * DIM + q * 4);
        float xs[4] = {v.x, v.y, v.z, v.w};
        f16x4 hh, lo;
        #pragma unroll
        for (int i = 0; i < 4; ++i) {
            const float m2 = -2.0f * xs[i];      // planes carry -2z
            _Float16 h = (_Float16)m2;
            hh[i] = h;
            lo[i] = (_Float16)(m2 - (float)h);
        }
        char* base = smem + r * 1040 + q * 8;
        *(f16x4*)(base) = hh;                    // hi plane
        *(f16x4*)(base + 512) = lo;              // lo plane
    }
    run[tid] = ~0ULL;

    f16x8 bz;                                    // aug B: B[k0]=B[k1]=1 (hi1=0), else 0
    #pragma unroll
    for (int i = 0; i < 8; ++i) bz[i] = (_Float16)0;
    if (hi1 == 0) { bz[0] = (_Float16)1; bz[1] = (_Float16)1; }

    f32x16 zacc;                                 // constant C=0 for aug MFMAs
    #pragma unroll
    for (int e = 0; e < 16; ++e) zacc[e] = 0.0f;

    const f16x8* eb  = (const f16x8*)et;
    const f16x8* ebL = eb + 262144;              // lo plane
    const int laneU = lo5 * 2 + hi1;             // loop-invariant A voffset (units)
    const char* zb = smem + (lo5 * 1040 + hi1 * 16);

    // prefetch aug-A for ci=0 (hi1=1 lanes get other norms: finite, x0 in MFMA)
    f16x8 paug[2];
    {
        const int c0 = codeS + w * 64;
        paug[0] = eb[(size_t)524288 + c0 + lo5];
        paug[1] = eb[(size_t)524288 + c0 + 32 + lo5];
    }
    __syncthreads();

    for (int ci = 0; ci < 8; ++ci) {
        const int c0 = codeS + ci * 512 + w * 64;
        f32x16 acc[2][2];

        // aug-first: acc = ||e||^2 broadcast (also the zero-init)
        __builtin_amdgcn_s_setprio(1);
        #pragma unroll
        for (int mt = 0; mt < 2; ++mt)
            #pragma unroll
            for (int nt = 0; nt < 2; ++nt)
                acc[mt][nt] = __builtin_amdgcn_mfma_f32_32x32x16_f16(paug[mt], bz, zacc, 0, 0, 0);
        __builtin_amdgcn_s_setprio(0);

        if (ci < 7) {                            // prefetch aug-A for ci+1
            const int c1 = codeS + (ci + 1) * 512 + w * 64;
            paug[0] = eb[(size_t)524288 + c1 + lo5];
            paug[1] = eb[(size_t)524288 + c1 + 32 + lo5];
        }

        const size_t cu = (size_t)c0 * 2 + laneU;
        #pragma unroll 4
        for (int ksg = 0; ksg < 16; ++ksg) {
            const size_t ub = (size_t)ksg * 16384 + cu;
            f16x8 ah[2], al[2];
            ah[0] = eb[ub];       ah[1] = eb[ub + 64];
            al[0] = ebL[ub];      al[1] = ebL[ub + 64];
            f16x8 bh[2], bl[2];
            #pragma unroll
            for (int nt = 0; nt < 2; ++nt) {
                bh[nt] = *(const f16x8*)(zb + (ksg * 32 + nt * 33280));
                bl[nt] = *(const f16x8*)(zb + (ksg * 32 + nt * 33280 + 512));
            }
            __builtin_amdgcn_s_setprio(1);
            #pragma unroll
            for (int mt = 0; mt < 2; ++mt)
                #pragma unroll
                for (int nt = 0; nt < 2; ++nt) {
                    acc[mt][nt] = __builtin_amdgcn_mfma_f32_32x32x16_f16(ah[mt], bh[nt], acc[mt][nt], 0, 0, 0);
                    acc[mt][nt] = __builtin_amdgcn_mfma_f32_32x32x16_f16(ah[mt], bl[nt], acc[mt][nt], 0, 0, 0);
                    acc[mt][nt] = __builtin_amdgcn_mfma_f32_32x32x16_f16(al[mt], bh[nt], acc[mt][nt], 0, 0, 0);
                }
            __builtin_amdgcn_s_setprio(0);
        }

        // ---- fold: f32 min-tree + first-match index, one packkey per nt ----
        #pragma unroll
        for (int nt = 0; nt < 2; ++nt) {
            float mm[16];
            #pragma unroll
            for (int r = 0; r < 16; ++r)
                mm[r] = fminf(acc[0][nt][r], acc[1][nt][r]);
            #pragma unroll
            for (int s2 = 8; s2 > 0; s2 >>= 1)
                #pragma unroll
                for (int r = 0; r < 8; ++r)
                    if (r < s2) mm[r] = fminf(mm[r], mm[r + s2]);
            const float m = mm[0];
            int rel = 64;                        // sentinel; rc max 59
            #pragma unroll
            for (int mt = 0; mt < 2; ++mt)
                #pragma unroll
                for (int r = 0; r < 16; ++r) {
                    const int rc = mt * 32 + (r & 3) + 8 * (r >> 2);
                    const int cand = (acc[mt][nt][r] == m) ? rc : 64;
                    rel = cand < rel ? cand : rel;   // monotone rc => lowest code wins
                }
            u64 best = packkey(m, c0 + 4 * hi1 + rel);
            const u64 o = __shfl_xor(best, 32, 64);  // merge code-halves (same row)
            if (o < best) best = o;
            if (hi1 == 0) {
                u64* p = &run[w * 64 + nt * 32 + lo5];   // sole writer per slot
                if (best < *p) *p = best;
            }
        }
    }

    __syncthreads();
    if (tid < 64) {
        u64 k = run[tid];
        #pragma unroll
        for (int w2 = 1; w2 < 8; ++w2) { u64 o = run[w2 * 64 + tid]; if (o < k) k = o; }
        pkeys[(size_t)sp * N_ROWS + row0 + tid] = k;
    }
}

// ---------------- final: merge 2 splits, idx, z_q gather, loss ----------------
__global__ __launch_bounds__(512)
void vq_final(const float* __restrict__ z, const float* __restrict__ emb,
              const u64* __restrict__ pkeys,
              float* __restrict__ zq_out, float* __restrict__ loss_out,
              float* __restrict__ idx_out) {
    __shared__ int best[64];
    const int t = threadIdx.x;
    const int row0 = blockIdx.x * 64;
    if (t < 64) {
        u64 k = pkeys[row0 + t];
        u64 o = pkeys[(size_t)N_ROWS + row0 + t];
        if (o < k) k = o;
        const int code = (int)(k & 0xFFFFFFFFu);
        best[t] = code;
        idx_out[row0 + t] = (float)code;
    }
    __syncthreads();
    const int wave = t >> 6, lane = t & 63;
    float lsum = 0.0f;
    #pragma unroll
    for (int rr = 0; rr < 8; ++rr) {
        const int rl = wave * 8 + rr;
        const int rg = row0 + rl;
        const int code = best[rl];
        float4 ev = *(const float4*)(emb + (size_t)code * DIM + lane * 4);
        float4 zv = *(const float4*)(z   + (size_t)rg   * DIM + lane * 4);
        float dx = ev.x - zv.x, dy = ev.y - zv.y;
        float dz = ev.z - zv.z, dw = ev.w - zv.w;
        lsum += dx * dx + dy * dy + dz * dz + dw * dw;
        *(float4*)(zq_out + (size_t)rg * DIM + lane * 4) = ev;
    }
    #pragma unroll
    for (int off = 32; off > 0; off >>= 1) lsum += __shfl_down(lsum, off, 64);
    if (lane == 0) atomicAdd(loss_out, lsum * (1.25f / (float)ZQ_ELEMS));
}

extern "C" void kernel_launch(void* const* d_in, const int* in_sizes, int n_in,
                              void* d_out, int out_size, void* d_ws, size_t ws_size,
                              hipStream_t stream) {
    const float* z   = (const float*)d_in[0];
    const float* emb = (const float*)d_in[1];
    float* out  = (float*)d_out;
    float* zq   = out;
    float* loss = out + ZQ_ELEMS;
    float* idx  = out + ZQ_ELEMS + 1;

    char* ws = (char*)d_ws;
    _Float16* et = (_Float16*)(ws + WS_ET);
    u64*   pk    = (u64*)(ws + WS_PK);

    static bool attr_set = false;
    if (!attr_set) {
        hipFuncSetAttribute((const void*)vq_main,
                            hipFuncAttributeMaxDynamicSharedMemorySize, 70656);
        attr_set = true;
    }

    vq_prep<<<256, 256, 0, stream>>>(emb, et, loss);
    vq_main<<<512, 512, 70656, stream>>>(z, et, pk);
    vq_final<<<N_ROWS / 64, 512, 0, stream>>>(z, emb, pk, zq, loss, idx);
}

// Round 4
// 276.945 us; speedup vs baseline: 1.0641x; 1.0641x over previous
//
#include <hip/hip_runtime.h>
#include <stdint.h>

// z: [16,1024,256] fp32 -> N=16384 rows, D=256
// embedding: [8192,256] fp32 -> K=8192 codes
// out = [ z_q (4194304 f32) | loss (1 f32) | indices (16384 as f32) ]
#define N_ROWS   16384
#define DIM      256
#define N_CODES  8192
#define ZQ_ELEMS 4194304

typedef _Float16 f16x8 __attribute__((ext_vector_type(8)));
typedef _Float16 f16x4 __attribute__((ext_vector_type(4)));
typedef float    f32x16 __attribute__((ext_vector_type(16)));
typedef unsigned long long u64;

// ---- workspace (bytes): et 8.52 MB | pkeys 128 KB  (total 8.65 MB) ----
// et layout in f16x8 units (16 B):
//   hi plane: ksg*16384 + code*2 + h     (ksg 0..15, h 0..1 -> k-octet 2ksg+h)
//   lo plane: +262144
//   aug:      524288 + code  ({||e||^2_hi, ||e||^2_lo, 0...})
// pkeys: ONE u64 per row, merged across the 4 code-splits by atomicMin.
#define WS_ET  0
#define WS_PK  (8519680)

static __device__ __forceinline__ u64 packkey(float d, int c) {
    unsigned int u = __float_as_uint(d);
    u ^= ((unsigned int)((int)u >> 31)) | 0x80000000u;   // monotone float map
    return ((u64)u << 32) | (unsigned int)c;             // min => (dist, then idx)
}

// ---------------- prep: e-only, 256 fat blocks x 32 codes; init pkeys ----------------
__global__ void vq_prep(const float* __restrict__ emb, _Float16* __restrict__ et,
                        u64* __restrict__ pkeys, float* __restrict__ loss_ptr) {
    __shared__ _Float16 sh[2][32][272];          // 34,816 B (272-stride: conflict-free)
    const int t = threadIdx.x, w = t >> 6, l = t & 63;
    if (blockIdx.x == 0 && t == 0) *loss_ptr = 0.0f;
    if (t < 64) pkeys[blockIdx.x * 64 + t] = ~0ULL;
    const int code0 = blockIdx.x * 32;
    #pragma unroll
    for (int j = 0; j < 8; ++j) {
        const int cl = w * 8 + j;
        float4 v = *(const float4*)(emb + (size_t)(code0 + cl) * DIM + l * 4);
        float xs[4] = {v.x, v.y, v.z, v.w};
        f16x4 hh, lo;
        float s = 0.0f;
        #pragma unroll
        for (int i = 0; i < 4; ++i) {
            _Float16 h = (_Float16)xs[i];
            hh[i] = h;
            lo[i] = (_Float16)(xs[i] - (float)h);
            s += xs[i] * xs[i];
        }
        *(f16x4*)&sh[0][cl][l * 4] = hh;
        *(f16x4*)&sh[1][cl][l * 4] = lo;
        #pragma unroll
        for (int off = 32; off > 0; off >>= 1) s += __shfl_down(s, off, 64);
        if (l == 0) {                            // aug: {norm_hi, norm_lo, 0..}
            _Float16 nh = (_Float16)s;
            _Float16 nl = (_Float16)(s - (float)nh);
            f16x8 aug;
            #pragma unroll
            for (int i = 0; i < 8; ++i) aug[i] = (_Float16)0;
            aug[0] = nh; aug[1] = nl;
            *(f16x8*)(et + ((size_t)524288 + code0 + cl) * 8) = aug;
        }
    }
    __syncthreads();
    #pragma unroll
    for (int pp = 0; pp < 8; ++pp) {             // 2048 units, 1-KB coalesced stores
        const int gi = pp * 256 + t;
        const int p = gi >> 10, ks = (gi >> 6) & 15, cl = (gi >> 1) & 31, h = gi & 1;
        f16x8 frag = *(const f16x8*)&sh[p][cl][ks * 16 + h * 8];
        const size_t unit = (size_t)p * 262144 + (size_t)ks * 16384
                          + (size_t)(code0 + cl) * 2 + h;
        *(f16x8*)(et + unit * 8) = frag;
    }
}

// ---------------- main: 128-row blocks, 4-way XCD-pinned code split ----------------
// grid 512 = 128 row-blocks x 4 code-splits; sp = blockIdx&3 so with round-robin
// blockIdx%8 -> XCD each XCD sees ONE split: its 2.1-MB code panel is L2-resident.
// 512 threads (8 waves, 2/SIMD, 1 blk/CU). A = e from global (L2-hit, contiguous
// 1-KB wave segments), B = z (-2z hi/lo f16) staged in-kernel, LDS row stride
// 1040 B (odd*16 -> conflict-free b128 reads). nt=4: 24 MFMA per 4 A-loads.
// Aug-MFMA-first with C=0 initializes acc AND adds ||e||^2.
// LDS: z 133,120 + run 8,192 = 141,312 B.
__global__ __launch_bounds__(512, 2)
void vq_main(const float* __restrict__ z, const _Float16* __restrict__ et,
             u64* __restrict__ pkeys) {
    extern __shared__ char smem[];
    u64* run = (u64*)(smem + 133120);            // [8][128]

    const int tid = threadIdx.x;
    const int w = tid >> 6, L = tid & 63, lo5 = L & 31, hi1 = L >> 5;
    const int rb = blockIdx.x >> 2, sp = blockIdx.x & 3;
    const int row0 = rb * 128, codeS = sp * 2048;

    // ---- stage z: coalesced f32 loads -> (-2z) hi/lo -> lane-linear ds_write ----
    const float* zr = z + (size_t)row0 * DIM;
    #pragma unroll
    for (int jj = 0; jj < 16; ++jj) {
        const int idx = jj * 512 + tid;          // float4 index in [0,8192)
        const int r = idx >> 6, q = idx & 63;    // row, dim-quad
        float4 v = *(const float4*)(zr + (size_t)r * DIM + q * 4);
        float xs[4] = {v.x, v.y, v.z, v.w};
        f16x4 hh, lo;
        #pragma unroll
        for (int i = 0; i < 4; ++i) {
            const float m2 = -2.0f * xs[i];      // planes carry -2z
            _Float16 h = (_Float16)m2;
            hh[i] = h;
            lo[i] = (_Float16)(m2 - (float)h);
        }
        char* base = smem + r * 1040 + q * 8;
        *(f16x4*)(base) = hh;                    // hi plane
        *(f16x4*)(base + 512) = lo;              // lo plane
    }
    run[tid] = ~0ULL;
    run[tid + 512] = ~0ULL;

    f16x8 bz;                                    // aug B: B[k0]=B[k1]=1 (hi1=0), else 0
    #pragma unroll
    for (int i = 0; i < 8; ++i) bz[i] = (_Float16)0;
    if (hi1 == 0) { bz[0] = (_Float16)1; bz[1] = (_Float16)1; }

    f32x16 zacc;                                 // constant C=0 for aug MFMAs
    #pragma unroll
    for (int e = 0; e < 16; ++e) zacc[e] = 0.0f;

    const f16x8* eb  = (const f16x8*)et;
    const f16x8* ebL = eb + 262144;              // lo plane
    const int laneU = lo5 * 2 + hi1;             // loop-invariant A voffset (units)
    const char* zbA = smem + (lo5 * 1040 + hi1 * 16);
    const char* zbB = zbA + 66560;               // rows 64..127 (imm stays < 64 KB)

    // prefetch aug-A for ci=0 (hi1=1 lanes get other norms: finite, x0 in MFMA)
    f16x8 paug[2];
    {
        const int c0 = codeS + w * 64;
        paug[0] = eb[(size_t)524288 + c0 + lo5];
        paug[1] = eb[(size_t)524288 + c0 + 32 + lo5];
    }
    __syncthreads();

    for (int ci = 0; ci < 4; ++ci) {
        const int c0 = codeS + ci * 512 + w * 64;
        f32x16 acc[2][4];

        // aug-first: acc = ||e||^2 broadcast (also the zero-init)
        __builtin_amdgcn_s_setprio(1);
        #pragma unroll
        for (int mt = 0; mt < 2; ++mt)
            #pragma unroll
            for (int nt = 0; nt < 4; ++nt)
                acc[mt][nt] = __builtin_amdgcn_mfma_f32_32x32x16_f16(paug[mt], bz, zacc, 0, 0, 0);
        __builtin_amdgcn_s_setprio(0);

        if (ci < 3) {                            // prefetch aug-A for ci+1
            const int c1 = codeS + (ci + 1) * 512 + w * 64;
            paug[0] = eb[(size_t)524288 + c1 + lo5];
            paug[1] = eb[(size_t)524288 + c1 + 32 + lo5];
        }

        const size_t cu = (size_t)c0 * 2 + laneU;
        #pragma unroll 4
        for (int ksg = 0; ksg < 16; ++ksg) {
            const size_t ub = (size_t)ksg * 16384 + cu;
            f16x8 ah[2], al[2];
            ah[0] = eb[ub];       ah[1] = eb[ub + 64];
            al[0] = ebL[ub];      al[1] = ebL[ub + 64];
            f16x8 bh[4], bl[4];
            #pragma unroll
            for (int nt = 0; nt < 4; ++nt) {
                const char* zp = (nt < 2) ? zbA : zbB;
                bh[nt] = *(const f16x8*)(zp + (ksg * 32 + (nt & 1) * 33280));
                bl[nt] = *(const f16x8*)(zp + (ksg * 32 + (nt & 1) * 33280 + 512));
            }
            __builtin_amdgcn_s_setprio(1);
            #pragma unroll
            for (int mt = 0; mt < 2; ++mt)
                #pragma unroll
                for (int nt = 0; nt < 4; ++nt) {
                    acc[mt][nt] = __builtin_amdgcn_mfma_f32_32x32x16_f16(ah[mt], bh[nt], acc[mt][nt], 0, 0, 0);
                    acc[mt][nt] = __builtin_amdgcn_mfma_f32_32x32x16_f16(ah[mt], bl[nt], acc[mt][nt], 0, 0, 0);
                    acc[mt][nt] = __builtin_amdgcn_mfma_f32_32x32x16_f16(al[mt], bh[nt], acc[mt][nt], 0, 0, 0);
                }
            __builtin_amdgcn_s_setprio(0);
        }

        // ---- fold: f32 min-tree + first-match index, one packkey per nt ----
        #pragma unroll
        for (int nt = 0; nt < 4; ++nt) {
            float mm[16];
            #pragma unroll
            for (int r = 0; r < 16; ++r)
                mm[r] = fminf(acc[0][nt][r], acc[1][nt][r]);
            #pragma unroll
            for (int s2 = 8; s2 > 0; s2 >>= 1)
                #pragma unroll
                for (int r = 0; r < 8; ++r)
                    if (r < s2) mm[r] = fminf(mm[r], mm[r + s2]);
            const float m = mm[0];
            int rel = 64;                        // sentinel; rc max 59
            #pragma unroll
            for (int mt = 0; mt < 2; ++mt)
                #pragma unroll
                for (int r = 0; r < 16; ++r) {
                    const int rc = mt * 32 + (r & 3) + 8 * (r >> 2);
                    const int cand = (acc[mt][nt][r] == m) ? rc : 64;
                    rel = cand < rel ? cand : rel;   // monotone rc => lowest code wins
                }
            u64 best = packkey(m, c0 + 4 * hi1 + rel);
            const u64 o = __shfl_xor(best, 32, 64);  // merge code-halves (same row)
            if (o < best) best = o;
            if (hi1 == 0) {
                u64* p = &run[w * 128 + nt * 32 + lo5];  // sole writer per slot
                if (best < *p) *p = best;
            }
        }
    }

    __syncthreads();
    if (tid < 128) {                             // merge 8 waves, then cross-split
        u64 k = run[tid];
        #pragma unroll
        for (int w2 = 1; w2 < 8; ++w2) { u64 o = run[w2 * 128 + tid]; if (o < k) k = o; }
        atomicMin(&pkeys[row0 + tid], k);
    }
}

// ---------------- final: idx, z_q gather, loss ----------------
__global__ __launch_bounds__(512)
void vq_final(const float* __restrict__ z, const float* __restrict__ emb,
              const u64* __restrict__ pkeys,
              float* __restrict__ zq_out, float* __restrict__ loss_out,
              float* __restrict__ idx_out) {
    __shared__ int best[64];
    const int t = threadIdx.x;
    const int row0 = blockIdx.x * 64;
    if (t < 64) {
        const u64 k = pkeys[row0 + t];
        const int code = (int)(k & 0xFFFFFFFFu);
        best[t] = code;
        idx_out[row0 + t] = (float)code;
    }
    __syncthreads();
    const int wave = t >> 6, lane = t & 63;
    float lsum = 0.0f;
    #pragma unroll
    for (int rr = 0; rr < 8; ++rr) {
        const int rl = wave * 8 + rr;
        const int rg = row0 + rl;
        const int code = best[rl];
        float4 ev = *(const float4*)(emb + (size_t)code * DIM + lane * 4);
        float4 zv = *(const float4*)(z   + (size_t)rg   * DIM + lane * 4);
        float dx = ev.x - zv.x, dy = ev.y - zv.y;
        float dz = ev.z - zv.z, dw = ev.w - zv.w;
        lsum += dx * dx + dy * dy + dz * dz + dw * dw;
        *(float4*)(zq_out + (size_t)rg * DIM + lane * 4) = ev;
    }
    #pragma unroll
    for (int off = 32; off > 0; off >>= 1) lsum += __shfl_down(lsum, off, 64);
    if (lane == 0) atomicAdd(loss_out, lsum * (1.25f / (float)ZQ_ELEMS));
}

extern "C" void kernel_launch(void* const* d_in, const int* in_sizes, int n_in,
                              void* d_out, int out_size, void* d_ws, size_t ws_size,
                              hipStream_t stream) {
    const float* z   = (const float*)d_in[0];
    const float* emb = (const float*)d_in[1];
    float* out  = (float*)d_out;
    float* zq   = out;
    float* loss = out + ZQ_ELEMS;
    float* idx  = out + ZQ_ELEMS + 1;

    char* ws = (char*)d_ws;
    _Float16* et = (_Float16*)(ws + WS_ET);
    u64*   pk    = (u64*)(ws + WS_PK);

    static bool attr_set = false;
    if (!attr_set) {
        hipFuncSetAttribute((const void*)vq_main,
                            hipFuncAttributeMaxDynamicSharedMemorySize, 141312);
        attr_set = true;
    }

    vq_prep<<<256, 256, 0, stream>>>(emb, et, pk, loss);
    vq_main<<<512, 512, 141312, stream>>>(z, et, pk);
    vq_final<<<N_ROWS / 64, 512, 0, stream>>>(z, emb, pk, zq, loss, idx);
}

// Round 5
// 274.321 us; speedup vs baseline: 1.0742x; 1.0096x over previous
//
#include <hip/hip_runtime.h>
#include <stdint.h>

// z: [16,1024,256] fp32 -> N=16384 rows, D=256
// embedding: [8192,256] fp32 -> K=8192 codes
// out = [ z_q (4194304 f32) | loss (1 f32) | indices (16384 as f32) ]
#define N_ROWS   16384
#define DIM      256
#define N_CODES  8192
#define ZQ_ELEMS 4194304

typedef _Float16 f16x8 __attribute__((ext_vector_type(8)));
typedef _Float16 f16x4 __attribute__((ext_vector_type(4)));
typedef float    f32x16 __attribute__((ext_vector_type(16)));
typedef unsigned long long u64;

// ---- workspace (bytes): et 8.52 MB | pkeys 128 KB  (total 8.65 MB) ----
// et layout in f16x8 units (16 B) — CONTIGUOUS PER SPLIT (L2 aliasing fix):
//   hi plane: p=0: sp*65536 + ksg*4096 + cw*2 + h   (sp=code>>11, cw=code&2047,
//             ksg 0..15, h 0..1 -> k-octet 2ksg+h); each split's panel is a
//             contiguous 1 MB -> uniform L2 set coverage (old 256-KB-strided
//             64-KB windows aliased 2 MB onto 512 sets = 1 MB capacity -> thrash).
//   lo plane: +262144
//   aug:      524288 + code  ({||e||^2_hi, ||e||^2_lo, 0...})
// pkeys: ONE u64 per row, merged across the 4 code-splits by atomicMin.
#define WS_ET  0
#define WS_PK  (8519680)

static __device__ __forceinline__ u64 packkey(float d, int c) {
    unsigned int u = __float_as_uint(d);
    u ^= ((unsigned int)((int)u >> 31)) | 0x80000000u;   // monotone float map
    return ((u64)u << 32) | (unsigned int)c;             // min => (dist, then idx)
}

// ---------------- prep: e-only, 256 fat blocks x 32 codes; init pkeys ----------------
__global__ void vq_prep(const float* __restrict__ emb, _Float16* __restrict__ et,
                        u64* __restrict__ pkeys, float* __restrict__ loss_ptr) {
    __shared__ _Float16 sh[2][32][272];          // 34,816 B
    const int t = threadIdx.x, w = t >> 6, l = t & 63;
    if (blockIdx.x == 0 && t == 0) *loss_ptr = 0.0f;
    if (t < 64) pkeys[blockIdx.x * 64 + t] = ~0ULL;
    const int code0 = blockIdx.x * 32;
    const int sp0 = code0 >> 11, cw0 = code0 & 2047;   // block never straddles a split
    #pragma unroll
    for (int j = 0; j < 8; ++j) {
        const int cl = w * 8 + j;
        float4 v = *(const float4*)(emb + (size_t)(code0 + cl) * DIM + l * 4);
        float xs[4] = {v.x, v.y, v.z, v.w};
        f16x4 hh, lo;
        float s = 0.0f;
        #pragma unroll
        for (int i = 0; i < 4; ++i) {
            _Float16 h = (_Float16)xs[i];
            hh[i] = h;
            lo[i] = (_Float16)(xs[i] - (float)h);
            s += xs[i] * xs[i];
        }
        *(f16x4*)&sh[0][cl][l * 4] = hh;
        *(f16x4*)&sh[1][cl][l * 4] = lo;
        #pragma unroll
        for (int off = 32; off > 0; off >>= 1) s += __shfl_down(s, off, 64);
        if (l == 0) {                            // aug: {norm_hi, norm_lo, 0..}
            _Float16 nh = (_Float16)s;
            _Float16 nl = (_Float16)(s - (float)nh);
            f16x8 aug;
            #pragma unroll
            for (int i = 0; i < 8; ++i) aug[i] = (_Float16)0;
            aug[0] = nh; aug[1] = nl;
            *(f16x8*)(et + ((size_t)524288 + code0 + cl) * 8) = aug;
        }
    }
    __syncthreads();
    #pragma unroll
    for (int pp = 0; pp < 8; ++pp) {             // 2048 units, 1-KB coalesced stores
        const int gi = pp * 256 + t;
        const int p = gi >> 10, ks = (gi >> 6) & 15, cl = (gi >> 1) & 31, h = gi & 1;
        f16x8 frag = *(const f16x8*)&sh[p][cl][ks * 16 + h * 8];
        const size_t unit = (size_t)p * 262144 + (size_t)sp0 * 65536
                          + (size_t)ks * 4096 + (size_t)(cw0 + cl) * 2 + h;
        *(f16x8*)(et + unit * 8) = frag;
    }
}

// ---------------- main: 128-row blocks, 4-way XCD-pinned code split ----------------
// grid 512 = 128 row-blocks x 4 code-splits; sp = blockIdx&3 (round-robin %8 -> XCD
// gives each XCD one split; its CONTIGUOUS 2.1-MB panel is truly L2-resident now).
// 512 threads (8 waves, 2/SIMD, 1 blk/CU). A = e from global with explicit
// one-ksg-ahead double-buffer prefetch (aN) + next-ci ksg0 prefetch before fold.
// B = z (-2z hi/lo f16) staged in-kernel, LDS row stride 1040 B (conflict-free).
// Aug-MFMA-first with C=0 initializes acc AND adds ||e||^2.
// LDS: z 133,120 + run 8,192 = 141,312 B.
__global__ __launch_bounds__(512, 2)
void vq_main(const float* __restrict__ z, const _Float16* __restrict__ et,
             u64* __restrict__ pkeys) {
    extern __shared__ char smem[];
    u64* run = (u64*)(smem + 133120);            // [8][128]

    const int tid = threadIdx.x;
    const int w = tid >> 6, L = tid & 63, lo5 = L & 31, hi1 = L >> 5;
    const int rb = blockIdx.x >> 2, sp = blockIdx.x & 3;
    const int row0 = rb * 128, codeS = sp * 2048;

    // ---- stage z: coalesced f32 loads -> (-2z) hi/lo -> lane-linear ds_write ----
    const float* zr = z + (size_t)row0 * DIM;
    #pragma unroll
    for (int jj = 0; jj < 16; ++jj) {
        const int idx = jj * 512 + tid;          // float4 index in [0,8192)
        const int r = idx >> 6, q = idx & 63;    // row, dim-quad
        float4 v = *(const float4*)(zr + (size_t)r * DIM + q * 4);
        float xs[4] = {v.x, v.y, v.z, v.w};
        f16x4 hh, lo;
        #pragma unroll
        for (int i = 0; i < 4; ++i) {
            const float m2 = -2.0f * xs[i];      // planes carry -2z
            _Float16 h = (_Float16)m2;
            hh[i] = h;
            lo[i] = (_Float16)(m2 - (float)h);
        }
        char* base = smem + r * 1040 + q * 8;
        *(f16x4*)(base) = hh;                    // hi plane
        *(f16x4*)(base + 512) = lo;              // lo plane
    }
    run[tid] = ~0ULL;
    run[tid + 512] = ~0ULL;

    f16x8 bz;                                    // aug B: B[k0]=B[k1]=1 (hi1=0), else 0
    #pragma unroll
    for (int i = 0; i < 8; ++i) bz[i] = (_Float16)0;
    if (hi1 == 0) { bz[0] = (_Float16)1; bz[1] = (_Float16)1; }

    f32x16 zacc;                                 // constant C=0 for aug MFMAs
    #pragma unroll
    for (int e = 0; e < 16; ++e) zacc[e] = 0.0f;

    const f16x8* eb  = (const f16x8*)et;
    const f16x8* ebL = eb + 262144;              // lo plane
    const int laneU = lo5 * 2 + hi1;             // loop-invariant A voffset (units)
    const size_t spB = (size_t)sp * 65536;
    const char* zbA = smem + (lo5 * 1040 + hi1 * 16);
    const char* zbB = zbA + 66560;               // rows 64..127 (imm stays < 64 KB)

    // prefetch aug-A for ci=0 (hi1=1 lanes get other norms: finite, x0 in MFMA)
    f16x8 paug[2];
    {
        const int c0 = codeS + w * 64;
        paug[0] = eb[(size_t)524288 + c0 + lo5];
        paug[1] = eb[(size_t)524288 + c0 + 32 + lo5];
    }
    // prefetch A ksg=0 of ci=0 (overlaps staging + barrier)
    f16x8 aC0, aC1, aC2, aC3;
    {
        const size_t cu = spB + (size_t)(w * 64) * 2 + laneU;
        aC0 = eb[cu]; aC1 = eb[cu + 64]; aC2 = ebL[cu]; aC3 = ebL[cu + 64];
    }
    __syncthreads();

    for (int ci = 0; ci < 4; ++ci) {
        const int c0 = codeS + ci * 512 + w * 64;
        const size_t cu = spB + (size_t)(ci * 512 + w * 64) * 2 + laneU;
        f32x16 acc[2][4];

        // aug-first: acc = ||e||^2 broadcast (also the zero-init)
        __builtin_amdgcn_s_setprio(1);
        #pragma unroll
        for (int mt = 0; mt < 2; ++mt)
            #pragma unroll
            for (int nt = 0; nt < 4; ++nt)
                acc[mt][nt] = __builtin_amdgcn_mfma_f32_32x32x16_f16(paug[mt], bz, zacc, 0, 0, 0);
        __builtin_amdgcn_s_setprio(0);

        if (ci < 3) {                            // prefetch aug-A for ci+1
            const int c1 = codeS + (ci + 1) * 512 + w * 64;
            paug[0] = eb[(size_t)524288 + c1 + lo5];
            paug[1] = eb[(size_t)524288 + c1 + 32 + lo5];
        }

        #pragma unroll 4
        for (int ksg = 0; ksg < 16; ++ksg) {
            // A prefetch for ksg+1 (ksg=15 -> phantom, in-bounds, unused)
            const size_t ubn = cu + (size_t)(ksg + 1) * 4096;
            f16x8 aN0 = eb[ubn], aN1 = eb[ubn + 64];
            f16x8 aN2 = ebL[ubn], aN3 = ebL[ubn + 64];

            // first nt-half
            {
                f16x8 bh0 = *(const f16x8*)(zbA + (ksg * 32));
                f16x8 bl0 = *(const f16x8*)(zbA + (ksg * 32 + 512));
                f16x8 bh1 = *(const f16x8*)(zbA + (ksg * 32 + 33280));
                f16x8 bl1 = *(const f16x8*)(zbA + (ksg * 32 + 33280 + 512));
                __builtin_amdgcn_s_setprio(1);
                acc[0][0] = __builtin_amdgcn_mfma_f32_32x32x16_f16(aC0, bh0, acc[0][0], 0, 0, 0);
                acc[0][0] = __builtin_amdgcn_mfma_f32_32x32x16_f16(aC0, bl0, acc[0][0], 0, 0, 0);
                acc[0][0] = __builtin_amdgcn_mfma_f32_32x32x16_f16(aC2, bh0, acc[0][0], 0, 0, 0);
                acc[0][1] = __builtin_amdgcn_mfma_f32_32x32x16_f16(aC0, bh1, acc[0][1], 0, 0, 0);
                acc[0][1] = __builtin_amdgcn_mfma_f32_32x32x16_f16(aC0, bl1, acc[0][1], 0, 0, 0);
                acc[0][1] = __builtin_amdgcn_mfma_f32_32x32x16_f16(aC2, bh1, acc[0][1], 0, 0, 0);
                acc[1][0] = __builtin_amdgcn_mfma_f32_32x32x16_f16(aC1, bh0, acc[1][0], 0, 0, 0);
                acc[1][0] = __builtin_amdgcn_mfma_f32_32x32x16_f16(aC1, bl0, acc[1][0], 0, 0, 0);
                acc[1][0] = __builtin_amdgcn_mfma_f32_32x32x16_f16(aC3, bh0, acc[1][0], 0, 0, 0);
                acc[1][1] = __builtin_amdgcn_mfma_f32_32x32x16_f16(aC1, bh1, acc[1][1], 0, 0, 0);
                acc[1][1] = __builtin_amdgcn_mfma_f32_32x32x16_f16(aC1, bl1, acc[1][1], 0, 0, 0);
                acc[1][1] = __builtin_amdgcn_mfma_f32_32x32x16_f16(aC3, bh1, acc[1][1], 0, 0, 0);
                __builtin_amdgcn_s_setprio(0);
            }
            // second nt-half
            {
                f16x8 bh2 = *(const f16x8*)(zbB + (ksg * 32));
                f16x8 bl2 = *(const f16x8*)(zbB + (ksg * 32 + 512));
                f16x8 bh3 = *(const f16x8*)(zbB + (ksg * 32 + 33280));
                f16x8 bl3 = *(const f16x8*)(zbB + (ksg * 32 + 33280 + 512));
                __builtin_amdgcn_s_setprio(1);
                acc[0][2] = __builtin_amdgcn_mfma_f32_32x32x16_f16(aC0, bh2, acc[0][2], 0, 0, 0);
                acc[0][2] = __builtin_amdgcn_mfma_f32_32x32x16_f16(aC0, bl2, acc[0][2], 0, 0, 0);
                acc[0][2] = __builtin_amdgcn_mfma_f32_32x32x16_f16(aC2, bh2, acc[0][2], 0, 0, 0);
                acc[0][3] = __builtin_amdgcn_mfma_f32_32x32x16_f16(aC0, bh3, acc[0][3], 0, 0, 0);
                acc[0][3] = __builtin_amdgcn_mfma_f32_32x32x16_f16(aC0, bl3, acc[0][3], 0, 0, 0);
                acc[0][3] = __builtin_amdgcn_mfma_f32_32x32x16_f16(aC2, bh3, acc[0][3], 0, 0, 0);
                acc[1][2] = __builtin_amdgcn_mfma_f32_32x32x16_f16(aC1, bh2, acc[1][2], 0, 0, 0);
                acc[1][2] = __builtin_amdgcn_mfma_f32_32x32x16_f16(aC1, bl2, acc[1][2], 0, 0, 0);
                acc[1][2] = __builtin_amdgcn_mfma_f32_32x32x16_f16(aC3, bh2, acc[1][2], 0, 0, 0);
                acc[1][3] = __builtin_amdgcn_mfma_f32_32x32x16_f16(aC1, bh3, acc[1][3], 0, 0, 0);
                acc[1][3] = __builtin_amdgcn_mfma_f32_32x32x16_f16(aC1, bl3, acc[1][3], 0, 0, 0);
                acc[1][3] = __builtin_amdgcn_mfma_f32_32x32x16_f16(aC3, bh3, acc[1][3], 0, 0, 0);
                __builtin_amdgcn_s_setprio(0);
            }
            aC0 = aN0; aC1 = aN1; aC2 = aN2; aC3 = aN3;
        }

        // prefetch A ksg=0 of next ci BEFORE the fold (hides L2 latency under fold)
        {
            const size_t cuN = spB + (size_t)((((ci + 1) & 3) * 512) + w * 64) * 2 + laneU;
            aC0 = eb[cuN]; aC1 = eb[cuN + 64]; aC2 = ebL[cuN]; aC3 = ebL[cuN + 64];
        }

        // ---- fold: f32 min-tree + first-match index, one packkey per nt ----
        #pragma unroll
        for (int nt = 0; nt < 4; ++nt) {
            float mm[16];
            #pragma unroll
            for (int r = 0; r < 16; ++r)
                mm[r] = fminf(acc[0][nt][r], acc[1][nt][r]);
            #pragma unroll
            for (int s2 = 8; s2 > 0; s2 >>= 1)
                #pragma unroll
                for (int r = 0; r < 8; ++r)
                    if (r < s2) mm[r] = fminf(mm[r], mm[r + s2]);
            const float m = mm[0];
            int rel = 64;                        // sentinel; rc max 59
            #pragma unroll
            for (int mt = 0; mt < 2; ++mt)
                #pragma unroll
                for (int r = 0; r < 16; ++r) {
                    const int rc = mt * 32 + (r & 3) + 8 * (r >> 2);
                    const int cand = (acc[mt][nt][r] == m) ? rc : 64;
                    rel = cand < rel ? cand : rel;   // monotone rc => lowest code wins
                }
            u64 best = packkey(m, c0 + 4 * hi1 + rel);
            const u64 o = __shfl_xor(best, 32, 64);  // merge code-halves (same row)
            if (o < best) best = o;
            if (hi1 == 0) {
                u64* p = &run[w * 128 + nt * 32 + lo5];  // sole writer per slot
                if (best < *p) *p = best;
            }
        }
    }

    __syncthreads();
    if (tid < 128) {                             // merge 8 waves, then cross-split
        u64 k = run[tid];
        #pragma unroll
        for (int w2 = 1; w2 < 8; ++w2) { u64 o = run[w2 * 128 + tid]; if (o < k) k = o; }
        atomicMin(&pkeys[row0 + tid], k);
    }
}

// ---------------- final: idx, z_q gather, loss ----------------
__global__ __launch_bounds__(512)
void vq_final(const float* __restrict__ z, const float* __restrict__ emb,
              const u64* __restrict__ pkeys,
              float* __restrict__ zq_out, float* __restrict__ loss_out,
              float* __restrict__ idx_out) {
    __shared__ int best[64];
    const int t = threadIdx.x;
    const int row0 = blockIdx.x * 64;
    if (t < 64) {
        const u64 k = pkeys[row0 + t];
        const int code = (int)(k & 0xFFFFFFFFu);
        best[t] = code;
        idx_out[row0 + t] = (float)code;
    }
    __syncthreads();
    const int wave = t >> 6, lane = t & 63;
    float lsum = 0.0f;
    #pragma unroll
    for (int rr = 0; rr < 8; ++rr) {
        const int rl = wave * 8 + rr;
        const int rg = row0 + rl;
        const int code = best[rl];
        float4 ev = *(const float4*)(emb + (size_t)code * DIM + lane * 4);
        float4 zv = *(const float4*)(z   + (size_t)rg   * DIM + lane * 4);
        float dx = ev.x - zv.x, dy = ev.y - zv.y;
        float dz = ev.z - zv.z, dw = ev.w - zv.w;
        lsum += dx * dx + dy * dy + dz * dz + dw * dw;
        *(float4*)(zq_out + (size_t)rg * DIM + lane * 4) = ev;
    }
    #pragma unroll
    for (int off = 32; off > 0; off >>= 1) lsum += __shfl_down(lsum, off, 64);
    if (lane == 0) atomicAdd(loss_out, lsum * (1.25f / (float)ZQ_ELEMS));
}

extern "C" void kernel_launch(void* const* d_in, const int* in_sizes, int n_in,
                              void* d_out, int out_size, void* d_ws, size_t ws_size,
                              hipStream_t stream) {
    const float* z   = (const float*)d_in[0];
    const float* emb = (const float*)d_in[1];
    float* out  = (float*)d_out;
    float* zq   = out;
    float* loss = out + ZQ_ELEMS;
    float* idx  = out + ZQ_ELEMS + 1;

    char* ws = (char*)d_ws;
    _Float16* et = (_Float16*)(ws + WS_ET);
    u64*   pk    = (u64*)(ws + WS_PK);

    static bool attr_set = false;
    if (!attr_set) {
        hipFuncSetAttribute((const void*)vq_main,
                            hipFuncAttributeMaxDynamicSharedMemorySize, 141312);
        attr_set = true;
    }

    vq_prep<<<256, 256, 0, stream>>>(emb, et, pk, loss);
    vq_main<<<512, 512, 141312, stream>>>(z, et, pk);
    vq_final<<<N_ROWS / 64, 512, 0, stream>>>(z, emb, pk, zq, loss, idx);
}